// Round 10
// baseline (3117.243 us; speedup 1.0000x reference)
//
#include <hip/hip_runtime.h>

typedef __attribute__((ext_vector_type(8))) short bf16x8;
typedef __attribute__((ext_vector_type(4))) float f32x4;

#define NWG 256  // 256 single-wave WGs: rt = blockIdx&7 (XCD under round-robin), ct = blockIdx>>3

template <bool B> struct BoolC { static constexpr bool value = B; };

__device__ __forceinline__ unsigned short f2bf(float f) {
  union { float f; unsigned u; } v; v.f = f;
  unsigned r = v.u + 0x7FFFu + ((v.u >> 16) & 1u);
  return (unsigned short)(r >> 16);
}

__device__ __forceinline__ float bf2f(unsigned short u) {
  union { unsigned u; float f; } v; v.u = (unsigned)u << 16;
  return v.f;
}

__device__ __forceinline__ float fast_tanh(float x) {
  float ax = fminf(fabsf(x), 15.f);
  float e = __expf(2.f * ax);
  float t = (e - 1.f) / (e + 1.f);
  return copysignf(t, x);
}

// FAST (XCD-local): plain loads; L1 invalidated (with waitcnt separation) before
// cross-CU reads -> served by the XCD-shared L2. SLOW: sc1 device scope (r7-proven).
#define LDH_F(d, b, O) \
  asm volatile("global_load_dwordx4 %0, %1, off offset:" #O : "=v"(d) : "v"(b))
#define LDH_S(d, b, O) \
  asm volatile("global_load_dwordx4 %0, %1, off offset:" #O " sc1" : "=v"(d) : "v"(b))
#define LDH16_F(A, B)            \
  LDH_F(A[0], B, 0);   LDH_F(A[1], B, 64);  LDH_F(A[2], B, 128); LDH_F(A[3], B, 192);  \
  LDH_F(A[4], B, 256); LDH_F(A[5], B, 320); LDH_F(A[6], B, 384); LDH_F(A[7], B, 448);  \
  LDH_F(A[8], B, 512); LDH_F(A[9], B, 576); LDH_F(A[10], B, 640); LDH_F(A[11], B, 704); \
  LDH_F(A[12], B, 768); LDH_F(A[13], B, 832); LDH_F(A[14], B, 896); LDH_F(A[15], B, 960)
#define LDH16_S(A, B)            \
  LDH_S(A[0], B, 0);   LDH_S(A[1], B, 64);  LDH_S(A[2], B, 128); LDH_S(A[3], B, 192);  \
  LDH_S(A[4], B, 256); LDH_S(A[5], B, 320); LDH_S(A[6], B, 384); LDH_S(A[7], B, 448);  \
  LDH_S(A[8], B, 512); LDH_S(A[9], B, 576); LDH_S(A[10], B, 640); LDH_S(A[11], B, 704); \
  LDH_S(A[12], B, 768); LDH_S(A[13], B, 832); LDH_S(A[14], B, 896); LDH_S(A[15], B, 960)

// Poll group's 32 per-wave flags (64B-strided lines), lane-parallel.
// FAST: inv L1, WAIT for inv, then load (fixes round-9's inv/load race).
template <bool FAST>
__device__ __forceinline__ void poll_flags(const unsigned* p, unsigned tgt, int& budget) {
  while (true) {
    unsigned v;
    if (FAST)
      asm volatile("buffer_inv sc0\n\t"
                   "s_waitcnt vmcnt(0)\n\t"
                   "global_load_dword %0, %1, off\n\t"
                   "s_waitcnt vmcnt(0)" : "=v"(v) : "v"(p) : "memory");
    else
      asm volatile("global_load_dword %0, %1, off sc1\n\t"
                   "s_waitcnt vmcnt(0)" : "=v"(v) : "v"(p) : "memory");
    if (__all((int)(v >= tgt))) break;
    if (--budget < 0) break;  // hang-proof
  }
}

template <bool FAST>
__device__ __forceinline__ void st2h(unsigned* p, unsigned w0, unsigned w1) {
  if (FAST) {  // plain write-through: lands in XCD-shared L2
    asm volatile("global_store_dword %0, %1, off" :: "v"(p), "v"(w0) : "memory");
    asm volatile("global_store_dword %0, %1, off offset:1024" :: "v"(p), "v"(w1) : "memory");
  } else {
    asm volatile("global_store_dword %0, %1, off sc1" :: "v"(p), "v"(w0) : "memory");
    asm volatile("global_store_dword %0, %1, off offset:1024 sc1" :: "v"(p), "v"(w1) : "memory");
  }
}

template <bool FAST>
__device__ __forceinline__ void st_flag(unsigned* p, unsigned v) {
  if (FAST) asm volatile("global_store_dword %0, %1, off" :: "v"(p), "v"(v) : "memory");
  else      asm volatile("global_store_dword %0, %1, off sc1" :: "v"(p), "v"(v) : "memory");
}

__device__ __forceinline__ void packpair(bool evenl, float v0, float v1, float v2, float v3,
                                         unsigned& w0, unsigned& w1) {
  unsigned lo = (unsigned)f2bf(v0) | ((unsigned)f2bf(v1) << 16);
  unsigned hi = (unsigned)f2bf(v2) | ((unsigned)f2bf(v3) << 16);
  unsigned send = evenl ? hi : lo;
  unsigned recv = __shfl_xor(send, 1, 64);
  if (evenl) {
    w0 = (lo & 0xffffu) | (recv << 16);
    w1 = (lo >> 16) | (recv & 0xffff0000u);
  } else {
    w0 = (recv & 0xffffu) | (hi << 16);
    w1 = (recv >> 16) | (hi & 0xffff0000u);
  }
}

// ---------- prep ----------
__global__ void prep_kernel(const float* __restrict__ i2h,
                            const float* __restrict__ h2h,
                            unsigned short* __restrict__ WiB,
                            unsigned short* __restrict__ WhB,
                            unsigned short* __restrict__ h0,
                            unsigned short* __restrict__ h1,
                            unsigned* __restrict__ bar,
                            unsigned* __restrict__ flags) {
  int i = blockIdx.x * 256 + threadIdx.x;  // 524288 = L*H*H
  WiB[i] = f2bf(i2h[i]);
  WhB[i] = f2bf(h2h[i]);
  if (i < 65536) { h0[i] = 0; h1[i] = 0; }
  if (i < 64) bar[i] = 0;
  if (i < 8704) flags[i] = 0;  // 4096 flag + 4096 probe-data + 256 xbuf + 256 xbuf2
}

// ---------- wc: Wc = Wi0 @ inW ; bc = Wi0 . inb + b0 ----------
__global__ __launch_bounds__(256) void wc_kernel(const float* __restrict__ inW,
                                                 const float* __restrict__ inb,
                                                 const float* __restrict__ i2h,
                                                 const float* __restrict__ hb,
                                                 unsigned short* __restrict__ WcB,
                                                 float* __restrict__ bc) {
  const int n = blockIdx.x, i = threadIdx.x;
  const float* wrow = i2h + (size_t)n * 512;
  float acc = 0.f;
  for (int k = 0; k < 512; ++k) acc += wrow[k] * inW[k * 256 + i];
  WcB[n * 256 + i] = f2bf(acc);
  if (i == 0) {
    float a2 = 0.f;
    for (int k = 0; k < 512; ++k) a2 += wrow[k] * inb[k];
    bc[n] = a2 + hb[n];
  }
}

// ---------- proj: U[s][b][n] = x[b,s,:] . Wc[n,:] + bc[n] ----------
__global__ __launch_bounds__(256) void proj_kernel(const float* __restrict__ x,
                                                   const unsigned short* __restrict__ WcB,
                                                   const float* __restrict__ bc,
                                                   unsigned short* __restrict__ U) {
  const int tid = threadIdx.x;
  const int ln = tid & 63, wv = tid >> 6;
  const int wid = blockIdx.x * 4 + wv;
  const int mt = wid >> 5, nt = wid & 31;
  const int mrow = ln & 15, quad = ln >> 4, koff = quad * 8;
  const float* arow = x + (size_t)(mt * 16 + mrow) * 256 + koff;
  const unsigned short* brow = WcB + (size_t)(nt * 16 + mrow) * 256 + koff;
  f32x4 acc = {0.f, 0.f, 0.f, 0.f};
#pragma unroll
  for (int kk = 0; kk < 8; ++kk) {
    const int ko = kk * 32;
    bf16x8 af;
#pragma unroll
    for (int j = 0; j < 8; ++j) af[j] = (short)f2bf(arow[ko + j]);
    bf16x8 bf = *(const bf16x8*)(brow + ko);
    acc = __builtin_amdgcn_mfma_f32_16x16x32_bf16(af, bf, acc, 0, 0, 0);
  }
  const int n = nt * 16 + mrow;
  const float bias = bc[n];
  const int m0 = mt * 16 + quad * 4;
#pragma unroll
  for (int r = 0; r < 4; ++r) {
    const int m = m0 + r;
    const int b = m >> 9, s = m & 511;
    U[((size_t)(s * 64 + b) << 9) + n] = f2bf(acc[r] + bias);
  }
}

// ---------- heavy grid barrier (slots 0,1,2), budget-escaped ----------
__device__ __forceinline__ void heavy_barrier(unsigned* bar, int slot) {
  __builtin_amdgcn_s_waitcnt(0);
  __syncthreads();
  if (threadIdx.x == 0) {
    __threadfence();  // release (wbl2: flushes dirty L2 lines to IF)
    unsigned prev = __hip_atomic_fetch_add(bar + slot, 1u, __ATOMIC_RELAXED, __HIP_MEMORY_SCOPE_AGENT);
    if (prev == NWG - 1) {
      __hip_atomic_store(bar + 16 + slot, 1u, __ATOMIC_RELAXED, __HIP_MEMORY_SCOPE_AGENT);
    } else {
      int b = 1 << 22;
      while (__hip_atomic_load(bar + 16 + slot, __ATOMIC_RELAXED, __HIP_MEMORY_SCOPE_AGENT) < 1u) {
        __builtin_amdgcn_s_sleep(1);
        if (--b < 0) break;
      }
    }
    __threadfence();  // acquire
  }
  __syncthreads();
}

__global__ __launch_bounds__(64, 1) void scan_kernel(const unsigned short* __restrict__ U,
                                                     const unsigned short* __restrict__ WiB,
                                                     const unsigned short* __restrict__ WhB,
                                                     const float* __restrict__ hb,
                                                     const float* __restrict__ outW,
                                                     const float* __restrict__ outb,
                                                     unsigned short* __restrict__ h0,
                                                     unsigned short* __restrict__ h1,
                                                     float* __restrict__ out,
                                                     unsigned* __restrict__ bar,
                                                     unsigned* __restrict__ flags) {
  const int ln = threadIdx.x;          // single wave per WG
  const int wid = blockIdx.x;          // 0..255
  const int rt = wid & 7;              // batch tile (8 rows) = XCD id under round-robin
  const int ct = wid >> 3;             // column tile 0..31
  const int mrow = ln & 15, quad = ln >> 4, koff = quad * 8;
  const int bA = rt * 8 + (mrow & 7);  // A-frag row = batch (rows 8..15 duplicate 0..7)
  const int n = ct * 16 + mrow;        // output column
  const bool evenl = (ln & 1) == 0;
  const int colp = n >> 1;
  const int hrow = quad * 4;                      // C-row base (quads 0,1 own real rows)
  const int urow = rt * 8 + ((quad & 1) << 2);    // U row base (dup for quads 2,3)

  // register/AGPR-resident weights: rows n of Wh0, Wi1, Wh1
  bf16x8 wf0[16], wf1[16], wf2[16];
  {
    const unsigned short* w0 = WhB + (size_t)n * 512 + koff;
    const unsigned short* w1 = WiB + (size_t)262144 + (size_t)n * 512 + koff;
    const unsigned short* w2 = WhB + (size_t)262144 + (size_t)n * 512 + koff;
#pragma unroll
    for (int kk = 0; kk < 16; ++kk) {
      wf0[kk] = *(const bf16x8*)(w0 + kk * 32);
      wf1[kk] = *(const bf16x8*)(w1 + kk * 32);
      wf2[kk] = *(const bf16x8*)(w2 + kk * 32);
    }
  }
  const float bias1 = hb[512 + n];
  const unsigned short* h0b = h0 + (size_t)bA * 512 + koff;
  const unsigned short* h1b = h1 + (size_t)bA * 512 + koff;
  const unsigned short* UB = U + ((size_t)urow << 9) + n;
  unsigned* myflag = flags + ((rt * 32 + ct) << 4);               // 64B-strided own line
  const unsigned* pollp = flags + ((rt * 32 + (ln & 31)) << 4);   // lane-parallel poll
  unsigned* mydata = flags + 4096 + ((rt * 32 + ct) << 4);        // probe data line
  const unsigned* datap = flags + 4096 + ((rt * 32 + (ln & 31)) << 4);
  unsigned* xbuf = flags + 8192;
  unsigned* xbuf2 = flags + 8448;

  // ---- phase 1: XCD-uniformity candidate check ----
  unsigned xcc = __builtin_amdgcn_s_getreg(6164) & 0xFu;  // hwreg(HW_REG_XCC_ID=20,0,4)
  if (ln == 0)
    __hip_atomic_store(xbuf + wid, xcc | 16u, __ATOMIC_RELAXED, __HIP_MEMORY_SCOPE_AGENT);
  heavy_barrier(bar, 0);
  unsigned xv = __hip_atomic_load(xbuf + ((ln & 31) * 8 + rt), __ATOMIC_RELAXED, __HIP_MEMORY_SCOPE_AGENT);
  unsigned xp = __hip_atomic_load(xbuf + (wid ^ 1), __ATOMIC_RELAXED, __HIP_MEMORY_SCOPE_AGENT);
  unsigned x0 = __shfl(xv, 0, 64);
  const bool cand = __all((int)(xv == x0)) && (xp != (xcc | 16u));

  // ---- phase 2: probe the FAST protocol (3 handshake rounds, data-verified) ----
  bool ok = cand;
  if (cand) {
    int pb = 1 << 13;
    for (int r = 1; r <= 3 && ok; ++r) {
      unsigned pat = 0xA5A50000u + (unsigned)r;
      if (ln == 0) {
        asm volatile("global_store_dword %0, %1, off" :: "v"(mydata), "v"(pat) : "memory");
        asm volatile("s_waitcnt vmcnt(0)" ::: "memory");
        asm volatile("global_store_dword %0, %1, off" :: "v"(myflag), "v"((unsigned)r) : "memory");
      }
      bool got = false;
      while (true) {
        unsigned v;
        asm volatile("buffer_inv sc0\n\ts_waitcnt vmcnt(0)\n\t"
                     "global_load_dword %0, %1, off\n\ts_waitcnt vmcnt(0)"
                     : "=v"(v) : "v"(pollp) : "memory");
        if (__all((int)(v >= (unsigned)r))) { got = true; break; }
        if (--pb < 0) break;
      }
      if (!got) { ok = false; break; }
      unsigned d;  // L1 was inv'd in the successful poll iteration
      asm volatile("global_load_dword %0, %1, off\n\ts_waitcnt vmcnt(0)"
                   : "=v"(d) : "v"(datap) : "memory");
      if (!__all((int)(d == pat))) ok = false;
    }
  }

  // ---- phase 3: agreement via proven agent-atomic channel ----
  if (ln == 0)
    __hip_atomic_store(xbuf2 + wid, ok ? 2u : 1u, __ATOMIC_RELAXED, __HIP_MEMORY_SCOPE_AGENT);
  heavy_barrier(bar, 2);  // release fence also flushes dirty probe-flag lines to IF
  unsigned av = __hip_atomic_load(xbuf2 + ((ln & 31) * 8 + rt), __ATOMIC_RELAXED, __HIP_MEMORY_SCOPE_AGENT);
  const bool fastpath = __all((int)(av == 2u));

  // U(0) preload
  unsigned short up0 = UB[0], up1 = UB[512], up2 = UB[1024], up3 = UB[1536];
  float t00 = 0, t01 = 0, t02 = 0, t03 = 0, t10 = 0, t11 = 0, t12 = 0, t13 = 0;
  int pbudget = 1 << 19;

  // flags monotonic: probe used 1..3; stage s polls s+3, stores s+4.
  auto loop = [&](auto FC) {
    constexpr bool FAST = decltype(FC)::value;
    for (int s = 0; s <= 512; ++s) {
      const int pd = s & 1, ps = pd ^ 1;
      const bool D0 = (s < 512), D1 = (s > 0);
      if (s) poll_flags<FAST>(pollp, (unsigned)(s + 3), pbudget);
      else if (FAST) asm volatile("buffer_inv sc0\n\ts_waitcnt vmcnt(0)" ::: "memory");
      asm volatile("" : "+v"(up0), "+v"(up1), "+v"(up2), "+v"(up3));

      bf16x8 h0f[16], h1f[16];
      const unsigned short* aH0 = h0b + (ps << 15);  // h0(s-1): L0.h2h == L1.i2h input
      const unsigned short* aH1 = h1b + (pd << 15);  // h1(s-2) for L1.h2h
      if (FAST) { LDH16_F(h0f, aH0); LDH16_F(h1f, aH1); }  // L1 inv'd -> L2-fresh
      else      { LDH16_S(h0f, aH0); LDH16_S(h1f, aH1); }

      asm volatile("s_waitcnt vmcnt(16)" ::: "memory");  // h0 ready; h1 in flight
#pragma unroll
      for (int kk = 0; kk < 16; ++kk) asm volatile("" : "+v"(h0f[kk]));

      f32x4 z = {0.f, 0.f, 0.f, 0.f};
      f32x4 acc0 = z, a1a = z, a1b = z;
#pragma unroll
      for (int kk = 0; kk < 16; ++kk) {
        if (D0) acc0 = __builtin_amdgcn_mfma_f32_16x16x32_bf16(h0f[kk], wf0[kk], acc0, 0, 0, 0);
        if (D1) a1a = __builtin_amdgcn_mfma_f32_16x16x32_bf16(h0f[kk], wf1[kk], a1a, 0, 0, 0);
      }

      if (D0) {  // layer0 output t=s -> h0[pd]
        float v0 = fast_tanh(acc0[0] + bf2f(up0));
        float v1 = fast_tanh(acc0[1] + bf2f(up1));
        float v2 = fast_tanh(acc0[2] + bf2f(up2));
        float v3 = fast_tanh(acc0[3] + bf2f(up3));
        unsigned w0, w1;
        packpair(evenl, v0, v1, v2, v3, w0, w1);
        if (quad < 2) {
          int row = rt * 8 + hrow + (evenl ? 0 : 2);
          st2h<FAST>((unsigned*)h0 + (pd << 14) + row * 256 + colp, w0, w1);
        }
        if (s == 511) { t00 = v0; t01 = v1; t02 = v2; t03 = v3; }
      }

      if (D0) asm volatile("s_waitcnt vmcnt(2)" ::: "memory");  // h1 done (in-order), stores in flight
      else    asm volatile("s_waitcnt vmcnt(0)" ::: "memory");
#pragma unroll
      for (int kk = 0; kk < 16; ++kk) asm volatile("" : "+v"(h1f[kk]));

      if (D1) {  // layer1 output t=s-1 -> h1[ps]
#pragma unroll
        for (int kk = 0; kk < 16; ++kk)
          a1b = __builtin_amdgcn_mfma_f32_16x16x32_bf16(h1f[kk], wf2[kk], a1b, 0, 0, 0);
        float v0 = fast_tanh(a1a[0] + a1b[0] + bias1);
        float v1 = fast_tanh(a1a[1] + a1b[1] + bias1);
        float v2 = fast_tanh(a1a[2] + a1b[2] + bias1);
        float v3 = fast_tanh(a1a[3] + a1b[3] + bias1);
        unsigned w0, w1;
        packpair(evenl, v0, v1, v2, v3, w0, w1);
        if (quad < 2) {
          int row = rt * 8 + hrow + (evenl ? 0 : 2);
          st2h<FAST>((unsigned*)h1 + (ps << 14) + row * 256 + colp, w0, w1);
        }
        if (s == 512) { t10 = v0; t11 = v1; t12 = v2; t13 = v3; }
      }

      asm volatile("s_waitcnt vmcnt(0)" ::: "memory");  // h stores committed (L2 in FAST)
      if (ln == 0) st_flag<FAST>(myflag, (unsigned)(s + 4));

      if (s <= 510) {  // U(s+1) prefetch: latency hides in next poll
        const unsigned short* un = UB + ((size_t)(s + 1) << 15);
        up0 = un[0]; up1 = un[512]; up2 = un[1024]; up3 = un[1536];
      }
    }
  };
  if (fastpath) loop(BoolC<true>{});
  else          loop(BoolC<false>{});

  // hT from saved registers (plain stores; flushed by barrier release fence)
  if (quad < 2) {
    float* o = out + 16384 + (size_t)(rt * 8 + hrow) * 512 + n;  // hT[0]
    o[0] = t00; o[512] = t01; o[1024] = t02; o[1536] = t03;
    float* o1 = o + 32768;                                        // hT[1]
    o1[0] = t10; o1[512] = t11; o1[1024] = t12; o1[1536] = t13;
  }
  heavy_barrier(bar, 1);

  // output = hT[1] @ out_W.T + out_b
  const int idx = wid * 64 + ln;  // 0..16383
  const int b = idx >> 8, o = idx & 255;
  const float* hr = out + 16384 + 32768 + (b << 9);
  const float* wr = outW + (o << 9);
  float s0 = 0.f, s1 = 0.f;
  for (int k = 0; k < 512; k += 8) {
    float4 h4 = *(const float4*)(hr + k);
    float4 w4 = *(const float4*)(wr + k);
    s0 += h4.x * w4.x + h4.y * w4.y + h4.z * w4.z + h4.w * w4.w;
    float4 h5 = *(const float4*)(hr + k + 4);
    float4 w5 = *(const float4*)(wr + k + 4);
    s1 += h5.x * w5.x + h5.y * w5.y + h5.z * w5.z + h5.w * w5.w;
  }
  out[idx] = s0 + s1 + outb[o];
}

extern "C" void kernel_launch(void* const* d_in, const int* in_sizes, int n_in,
                              void* d_out, int out_size, void* d_ws, size_t ws_size,
                              hipStream_t stream) {
  const float* x = (const float*)d_in[0];
  const float* inW = (const float*)d_in[1];
  const float* inb = (const float*)d_in[2];
  const float* i2h = (const float*)d_in[3];
  const float* h2h = (const float*)d_in[4];
  const float* hbias = (const float*)d_in[5];
  const float* outW = (const float*)d_in[6];
  const float* outb = (const float*)d_in[7];
  float* out = (float*)d_out;

  char* w = (char*)d_ws;
  unsigned short* WiB = (unsigned short*)w;                               // 1 MB
  unsigned short* WhB = (unsigned short*)(w + (1u << 20));                // 1 MB
  unsigned short* WcB = (unsigned short*)(w + (2u << 20));                // 256 KB
  float* bc = (float*)(w + (2u << 20) + (256u << 10));                    // 4 KB
  unsigned short* h0 = (unsigned short*)(w + (2u << 20) + (260u << 10));  // 128 KB
  unsigned short* h1 = (unsigned short*)(w + (2u << 20) + (388u << 10));  // 128 KB
  unsigned* bar = (unsigned*)(w + (2u << 20) + (516u << 10));             // 4 KB
  unsigned* flags = (unsigned*)(w + (2u << 20) + (520u << 10));           // 35 KB (8704 dwords)
  unsigned short* U = (unsigned short*)(w + (2u << 20) + (576u << 10));   // 32 MB

  prep_kernel<<<2048, 256, 0, stream>>>(i2h, h2h, WiB, WhB, h0, h1, bar, flags);
  wc_kernel<<<512, 256, 0, stream>>>(inW, inb, i2h, hbias, WcB, bc);
  proj_kernel<<<16384, 256, 0, stream>>>(x, WcB, bc, U);
  scan_kernel<<<NWG, 64, 0, stream>>>(U, WiB, WhB, hbias, outW, outb, h0, h1, out, bar, flags);
}